// Round 4
// baseline (1240.744 us; speedup 1.0000x reference)
//
#include <hip/hip_runtime.h>

typedef unsigned short u16;
typedef __bf16 bf16x8 __attribute__((ext_vector_type(8)));
typedef float f32x4 __attribute__((ext_vector_type(4)));

__device__ __forceinline__ u16 f2bf(float f) {
  unsigned int u = __builtin_bit_cast(unsigned int, f);
  u += 0x7fffu + ((u >> 16) & 1u);
  return (u16)(u >> 16);
}

// ---------------- WT[j][c] = sum_s rmsw[s*1024+c] * Wdyn[(s*1024+c)*24 + j] ------------
// TRANSPOSED layout (24 x 1024) so prep_tokens reads are lane-coalesced.
__global__ __launch_bounds__(256) void weff_kernel(const float* __restrict__ rmsw,
                                                   const float* __restrict__ Wdyn,
                                                   float* __restrict__ WT) {
  int idx = blockIdx.x * 256 + threadIdx.x;  // 24576 threads
  int j = idx >> 10, c = idx & 1023;
  float s = 0.f;
#pragma unroll
  for (int st = 0; st < 4; ++st) {
    int r = st * 1024 + c;
    s += rmsw[r] * Wdyn[(long)r * 24 + j];
  }
  WT[idx] = s;
}

// ---------------- transpose fp32 (R x C) -> bf16 (C x R) --------------------------------
__global__ __launch_bounds__(256) void transpose_kernel(const float* __restrict__ src,
                                                        u16* __restrict__ dst,
                                                        int R, int C) {
  __shared__ float tile[32][33];
  int tx = threadIdx.x & 31, ty = threadIdx.x >> 5;  // 32 x 8
  long c0 = (long)blockIdx.x * 32, r0 = (long)blockIdx.y * 32;
#pragma unroll
  for (int k = 0; k < 4; ++k)
    tile[ty + 8 * k][tx] = src[(r0 + ty + 8 * k) * C + c0 + tx];
  __syncthreads();
#pragma unroll
  for (int k = 0; k < 4; ++k)
    dst[(c0 + ty + 8 * k) * R + r0 + tx] = f2bf(tile[tx][ty + 8 * k]);
}

// ---------------- per-token prep: rms, dynamic(24), gates, sinkhorn, preA ---------------
__global__ __launch_bounds__(256) void prep_tokens(
    const float* __restrict__ x, const float* __restrict__ WT,
    const float* __restrict__ bias_pre, const float* __restrict__ bias_post,
    const float* __restrict__ bias_res, const float* __restrict__ a_pre,
    const float* __restrict__ a_post, const float* __restrict__ a_res,
    u16* __restrict__ preA, float* __restrict__ scal) {
  const int t = blockIdx.x;
  const int tid = threadIdx.x;
  const float4 xv = *(const float4*)(x + (long)t * 1024 + tid * 4);
  float ssq = xv.x * xv.x + xv.y * xv.y + xv.z * xv.z + xv.w * xv.w;
  float raw[24];
  // WT[j][4*tid .. 4*tid+3]: float4 loads, consecutive lanes -> consecutive 16B  (coalesced)
#pragma unroll
  for (int j = 0; j < 24; ++j) {
    const float4 w = *(const float4*)(WT + (long)j * 1024 + tid * 4);
    raw[j] = xv.x * w.x + xv.y * w.y + xv.z * w.z + xv.w * w.w;
  }
  // wave64 butterfly reduce of 25 partials
#pragma unroll
  for (int m = 1; m < 64; m <<= 1) {
    ssq += __shfl_xor(ssq, m);
#pragma unroll
    for (int j = 0; j < 24; ++j) raw[j] += __shfl_xor(raw[j], m);
  }
  __shared__ float red[4][25];
  __shared__ float tot[25];
  const int lane = tid & 63, wv = tid >> 6;
  if (lane == 0) {
#pragma unroll
    for (int j = 0; j < 24; ++j) red[wv][j] = raw[j];
    red[wv][24] = ssq;
  }
  __syncthreads();
  if (tid < 25) tot[tid] = red[0][tid] + red[1][tid] + red[2][tid] + red[3][tid];
  __syncthreads();

  const float rms = sqrtf(tot[24] * (1.0f / 1024.0f) + 1e-8f);
  const float rinv = 1.0f / rms;

  const float ap = a_pre[0];
  float s_pre = 0.f;
#pragma unroll
  for (int i = 0; i < 4; ++i)
    s_pre += 1.f / (1.f + expf(-(ap * tot[i] * rinv + bias_pre[i])));

  unsigned int lo = (unsigned)f2bf(s_pre * xv.x) | ((unsigned)f2bf(s_pre * xv.y) << 16);
  unsigned int hi = (unsigned)f2bf(s_pre * xv.z) | ((unsigned)f2bf(s_pre * xv.w) << 16);
  *(uint2*)(preA + (long)t * 1024 + tid * 4) = make_uint2(lo, hi);

  // sinkhorn on lanes 0..15 of wave 0 (lane = i*4 + j)
  if (tid < 16) {
    const float ar = a_res[0];
    float Mv = expf(ar * tot[8 + tid] * rinv + bias_res[tid]);
#pragma unroll
    for (int it = 0; it < 20; ++it) {
      float cs = Mv + __shfl_xor(Mv, 4);
      cs += __shfl_xor(cs, 8);
      Mv = Mv / (cs + 1e-8f);   // col normalize (axis=-2)
      float rs = Mv + __shfl_xor(Mv, 1);
      rs += __shfl_xor(rs, 2);
      Mv = Mv / (rs + 1e-8f);   // row normalize (axis=-1)
    }
    float rs = Mv + __shfl_xor(Mv, 1);
    rs += __shfl_xor(rs, 2);
    if ((tid & 3) == 0) scal[(long)t * 8 + (tid >> 2)] = rs;  // r_i
  }
  if (tid < 4) {
    const float apo = a_post[0];
    float hp = 2.f / (1.f + expf(-(apo * tot[4 + tid] * rinv + bias_post[tid])));
    scal[(long)t * 8 + 4 + tid] = hp;  // H_post
  }
}

// ---------------- bf16 MFMA GEMM: C(MxN) = A(MxK, row-major) * Bt(NxK)^T ----------------
// BM=BN=128, BK=64, 256 threads (4 waves, 2x2), each wave 4x4 of 16x16x32 MFMA.
// REGISTER-STAGED pipeline (no global_load_lds -> no vmcnt(0) drain at barriers):
//   coalesced dwordx4 global loads -> ping-pong VGPR sets -> ds_write_b128 with
//   XOR-swizzled LDS addresses -> conflict-free ds_read_b128 fragment reads.
// One barrier per K-tile (lgkm drain only). LDS dbuf 2x32 KiB.
// LDS layout: elem (m, kc16B) at u16 index m*64 + ((kc ^ (m&7))*8).
//   ds_write: lane l handles (row i*8 + l>>3, chunk l&7): 8 rows x full 128B, conflict-free.
//   ds_read frag: 16 rows x fixed kc: swizzle spreads 8-row groups over all banks, 2-way max.
// EPI: 0 = gelu -> bf16 dst (ld N) | 1 = build merged (ld 4096) | 2 = +bias+x -> fp32
template <int EPI>
__global__ __launch_bounds__(256) void gemm_bf16(const u16* __restrict__ A,
                                                 const u16* __restrict__ Bt,
                                                 const int K, const int N,
                                                 const float* __restrict__ bias,
                                                 const float* __restrict__ X,
                                                 const float* __restrict__ scal,
                                                 void* __restrict__ dstv) {
  __shared__ __attribute__((aligned(16))) u16 As[2][128 * 64];
  __shared__ __attribute__((aligned(16))) u16 Bs[2][128 * 64];
  const int tid = threadIdx.x;
  const int lane = tid & 63;
  const int wave = tid >> 6;
  const int wm = wave >> 1, wn = wave & 1;
  const long bm = (long)blockIdx.y * 128;
  const long bn = (long)blockIdx.x * 128;

  const int srow = lane >> 3;  // row within 8-row chunk
  const int skc = lane & 7;    // 16B chunk (lane-ordered -> coalesced global)

  const u16* Ag = A + (bm + wave * 32 + srow) * (long)K + skc * 8;
  const u16* Bg = Bt + (bn + wave * 32 + srow) * (long)K + skc * 8;
  // LDS dest for this lane's chunk of row group i: (r = wave*32 + i*8 + srow, chunk skc)
  //   idx = r*64 + ((skc ^ (r&7))*8);  r&7 == srow
  const int lws = (wave * 32 + srow) * 64 + ((skc ^ srow) * 8);

  f32x4 acc[4][4] = {};
  uint4 ra[2][4], rb[2][4];

  const int T = K >> 6;

  // prologue: load tile 0 into reg set 0
#pragma unroll
  for (int i = 0; i < 4; ++i) {
    ra[0][i] = *(const uint4*)(Ag + (long)i * 8 * K);
    rb[0][i] = *(const uint4*)(Bg + (long)i * 8 * K);
  }

  for (int kt = 0; kt < T; ++kt) {
    const int p = kt & 1;
    // prefetch tile kt+1 into the other reg set (long-latency, consumed next iter)
    if (kt + 1 < T) {
      const long ko = (long)(kt + 1) * 64;
#pragma unroll
      for (int i = 0; i < 4; ++i) {
        ra[p ^ 1][i] = *(const uint4*)(Ag + (long)i * 8 * K + ko);
        rb[p ^ 1][i] = *(const uint4*)(Bg + (long)i * 8 * K + ko);
      }
    }
    // stage tile kt regs -> LDS buf p (swizzled)
#pragma unroll
    for (int i = 0; i < 4; ++i) {
      *(uint4*)&As[p][lws + i * 512] = ra[p][i];
      *(uint4*)&Bs[p][lws + i * 512] = rb[p][i];
    }
    __syncthreads();  // lgkm drain only: no outstanding global->LDS ops
    // compute tile kt from buf p
#pragma unroll
    for (int h2 = 0; h2 < 2; ++h2) {
      const int kc = h2 * 4 + (lane >> 4);
      bf16x8 af[4], bfr[4];
#pragma unroll
      for (int i = 0; i < 4; ++i) {
        const int m = wm * 64 + i * 16 + (lane & 15);
        af[i] = *(const bf16x8*)&As[p][m * 64 + ((kc ^ (m & 7)) * 8)];
        const int n = wn * 64 + i * 16 + (lane & 15);
        bfr[i] = *(const bf16x8*)&Bs[p][n * 64 + ((kc ^ (n & 7)) * 8)];
      }
#pragma unroll
      for (int i = 0; i < 4; ++i)
#pragma unroll
        for (int j = 0; j < 4; ++j)
          acc[i][j] = __builtin_amdgcn_mfma_f32_16x16x32_bf16(af[i], bfr[j], acc[i][j], 0, 0, 0);
    }
    // NOTE: no second barrier needed: the iter-(kt+2) barrier transitively
    // guarantees all waves finished these reads before buf p is overwritten.
    __syncthreads();
  }

  // Epilogue. C/D layout: col = lane&15, row = (lane>>4)*4 + reg  [verified m89/m91]
  if constexpr (EPI == 0) {
    u16* dst = (u16*)dstv;
#pragma unroll
    for (int i = 0; i < 4; ++i)
#pragma unroll
      for (int r = 0; r < 4; ++r) {
        const long row = bm + wm * 64 + i * 16 + (lane >> 4) * 4 + r;
#pragma unroll
        for (int j = 0; j < 4; ++j) {
          const long col = bn + wn * 64 + j * 16 + (lane & 15);
          float v = acc[i][j][r] + bias[col];
          float g = 0.5f * v * (1.0f + erff(v * 0.70710678118654752f));
          dst[row * N + col] = f2bf(g);
        }
      }
  } else if constexpr (EPI == 1) {
    u16* dst = (u16*)dstv;  // merged, ld 4096
#pragma unroll
    for (int i = 0; i < 4; ++i)
#pragma unroll
      for (int r = 0; r < 4; ++r) {
        const long row = bm + wm * 64 + i * 16 + (lane >> 4) * 4 + r;
        const float4 rv = *(const float4*)(scal + row * 8);
        const float4 hv = *(const float4*)(scal + row * 8 + 4);
#pragma unroll
        for (int j = 0; j < 4; ++j) {
          const long col = bn + wn * 64 + j * 16 + (lane & 15);
          const float f = acc[i][j][r] + bias[col];
          const float xval = X[row * 1024 + col];
          const long base = row * 4096 + col;
          dst[base] = f2bf(rv.x * xval + hv.x * f);
          dst[base + 1024] = f2bf(rv.y * xval + hv.y * f);
          dst[base + 2048] = f2bf(rv.z * xval + hv.z * f);
          dst[base + 3072] = f2bf(rv.w * xval + hv.w * f);
        }
      }
  } else {
    float* dst = (float*)dstv;
#pragma unroll
    for (int i = 0; i < 4; ++i)
#pragma unroll
      for (int r = 0; r < 4; ++r) {
        const long row = bm + wm * 64 + i * 16 + (lane >> 4) * 4 + r;
#pragma unroll
        for (int j = 0; j < 4; ++j) {
          const long col = bn + wn * 64 + j * 16 + (lane & 15);
          dst[row * 1024 + col] = acc[i][j][r] + bias[col] + X[row * 1024 + col];
        }
      }
  }
}

extern "C" void kernel_launch(void* const* d_in, const int* in_sizes, int n_in,
                              void* d_out, int out_size, void* d_ws, size_t ws_size,
                              hipStream_t stream) {
  (void)in_sizes; (void)n_in; (void)out_size; (void)ws_size;
  const float* x = (const float*)d_in[0];
  const float* rmsw = (const float*)d_in[1];
  const float* Wdyn = (const float*)d_in[2];
  const float* bias_pre = (const float*)d_in[3];
  const float* bias_post = (const float*)d_in[4];
  const float* bias_res = (const float*)d_in[5];
  const float* a_pre = (const float*)d_in[6];
  const float* a_post = (const float*)d_in[7];
  const float* a_res = (const float*)d_in[8];
  const float* W1 = (const float*)d_in[9];
  const float* b1 = (const float*)d_in[10];
  const float* W2 = (const float*)d_in[11];
  const float* b2 = (const float*)d_in[12];
  const float* Wout = (const float*)d_in[13];
  const float* bout = (const float*)d_in[14];
  float* out = (float*)d_out;
  char* ws = (char*)d_ws;

  // workspace layout (bytes); merged overlaps preA (preA dead after GEMM1)
  constexpr size_t OFF_W1BT = 0;          // 4096x1024 bf16  (8 MiB)
  constexpr size_t OFF_W2BT = 8388608;    // 1024x4096 bf16  (8 MiB)
  constexpr size_t OFF_WOBT = 16777216;   // 1024x4096 bf16  (8 MiB)
  constexpr size_t OFF_WEFF = 25165824;   // 24x1024 f32     (96 KiB, transposed)
  constexpr size_t OFF_SCAL = 25264128;   // 8192x8 f32      (256 KiB)
  constexpr size_t OFF_H    = 25526272;   // 8192x4096 bf16  (64 MiB)
  constexpr size_t OFF_PREA = 92635136;   // 8192x1024 bf16  (16 MiB)
  constexpr size_t OFF_MERG = 92635136;   // 8192x4096 bf16  (64 MiB) -- total 159,744,000 B

  u16* W1bt = (u16*)(ws + OFF_W1BT);
  u16* W2bt = (u16*)(ws + OFF_W2BT);
  u16* Wobt = (u16*)(ws + OFF_WOBT);
  float* WT = (float*)(ws + OFF_WEFF);
  float* scal = (float*)(ws + OFF_SCAL);
  u16* h = (u16*)(ws + OFF_H);
  u16* preA = (u16*)(ws + OFF_PREA);
  u16* merged = (u16*)(ws + OFF_MERG);

  weff_kernel<<<96, 256, 0, stream>>>(rmsw, Wdyn, WT);
  transpose_kernel<<<dim3(128, 32), 256, 0, stream>>>(W1, W1bt, 1024, 4096);
  transpose_kernel<<<dim3(32, 128), 256, 0, stream>>>(W2, W2bt, 4096, 1024);
  transpose_kernel<<<dim3(32, 128), 256, 0, stream>>>(Wout, Wobt, 4096, 1024);
  prep_tokens<<<8192, 256, 0, stream>>>(x, WT, bias_pre, bias_post, bias_res,
                                        a_pre, a_post, a_res, preA, scal);
  // h = gelu(preA @ W1 + b1)                      M=8192 N=4096 K=1024
  gemm_bf16<0><<<dim3(32, 64), 256, 0, stream>>>(preA, W1bt, 1024, 4096, b1, nullptr, nullptr, h);
  // merged[:, s*1024+c] = r_s*x + hp_s*(h @ W2 + b2)   M=8192 N=1024 K=4096
  gemm_bf16<1><<<dim3(8, 64), 256, 0, stream>>>(h, W2bt, 4096, 1024, b2, x, scal, merged);
  // out = merged @ Wout + bout + x                M=8192 N=1024 K=4096
  gemm_bf16<2><<<dim3(8, 64), 256, 0, stream>>>(merged, Wobt, 4096, 1024, bout, x, nullptr, out);
}

// Round 5
// 1053.822 us; speedup vs baseline: 1.1774x; 1.1774x over previous
//
#include <hip/hip_runtime.h>

typedef unsigned short u16;
typedef __bf16 bf16x8 __attribute__((ext_vector_type(8)));
typedef float f32x4 __attribute__((ext_vector_type(4)));

__device__ __forceinline__ u16 f2bf(float f) {
  unsigned int u = __builtin_bit_cast(unsigned int, f);
  u += 0x7fffu + ((u >> 16) & 1u);
  return (u16)(u >> 16);
}

// ---------------- WT[j][c] = sum_s rmsw[s*1024+c] * Wdyn[(s*1024+c)*24 + j] ------------
__global__ __launch_bounds__(256) void weff_kernel(const float* __restrict__ rmsw,
                                                   const float* __restrict__ Wdyn,
                                                   float* __restrict__ WT) {
  int idx = blockIdx.x * 256 + threadIdx.x;  // 24576 threads
  int j = idx >> 10, c = idx & 1023;
  float s = 0.f;
#pragma unroll
  for (int st = 0; st < 4; ++st) {
    int r = st * 1024 + c;
    s += rmsw[r] * Wdyn[(long)r * 24 + j];
  }
  WT[idx] = s;
}

// ---------------- transpose fp32 (R x C) -> bf16 (C x R) --------------------------------
__global__ __launch_bounds__(256) void transpose_kernel(const float* __restrict__ src,
                                                        u16* __restrict__ dst,
                                                        int R, int C) {
  __shared__ float tile[32][33];
  int tx = threadIdx.x & 31, ty = threadIdx.x >> 5;  // 32 x 8
  long c0 = (long)blockIdx.x * 32, r0 = (long)blockIdx.y * 32;
#pragma unroll
  for (int k = 0; k < 4; ++k)
    tile[ty + 8 * k][tx] = src[(r0 + ty + 8 * k) * C + c0 + tx];
  __syncthreads();
#pragma unroll
  for (int k = 0; k < 4; ++k)
    dst[(c0 + ty + 8 * k) * R + r0 + tx] = f2bf(tile[tx][ty + 8 * k]);
}

// ---------------- per-token prep: rms, dynamic(24), gates, sinkhorn, preA ---------------
__global__ __launch_bounds__(256) void prep_tokens(
    const float* __restrict__ x, const float* __restrict__ WT,
    const float* __restrict__ bias_pre, const float* __restrict__ bias_post,
    const float* __restrict__ bias_res, const float* __restrict__ a_pre,
    const float* __restrict__ a_post, const float* __restrict__ a_res,
    u16* __restrict__ preA, float* __restrict__ scal) {
  const int t = blockIdx.x;
  const int tid = threadIdx.x;
  const float4 xv = *(const float4*)(x + (long)t * 1024 + tid * 4);
  float ssq = xv.x * xv.x + xv.y * xv.y + xv.z * xv.z + xv.w * xv.w;
  float raw[24];
#pragma unroll
  for (int j = 0; j < 24; ++j) {
    const float4 w = *(const float4*)(WT + (long)j * 1024 + tid * 4);
    raw[j] = xv.x * w.x + xv.y * w.y + xv.z * w.z + xv.w * w.w;
  }
#pragma unroll
  for (int m = 1; m < 64; m <<= 1) {
    ssq += __shfl_xor(ssq, m);
#pragma unroll
    for (int j = 0; j < 24; ++j) raw[j] += __shfl_xor(raw[j], m);
  }
  __shared__ float red[4][25];
  __shared__ float tot[25];
  const int lane = tid & 63, wv = tid >> 6;
  if (lane == 0) {
#pragma unroll
    for (int j = 0; j < 24; ++j) red[wv][j] = raw[j];
    red[wv][24] = ssq;
  }
  __syncthreads();
  if (tid < 25) tot[tid] = red[0][tid] + red[1][tid] + red[2][tid] + red[3][tid];
  __syncthreads();

  const float rms = sqrtf(tot[24] * (1.0f / 1024.0f) + 1e-8f);
  const float rinv = 1.0f / rms;

  const float ap = a_pre[0];
  float s_pre = 0.f;
#pragma unroll
  for (int i = 0; i < 4; ++i)
    s_pre += 1.f / (1.f + expf(-(ap * tot[i] * rinv + bias_pre[i])));

  unsigned int lo = (unsigned)f2bf(s_pre * xv.x) | ((unsigned)f2bf(s_pre * xv.y) << 16);
  unsigned int hi = (unsigned)f2bf(s_pre * xv.z) | ((unsigned)f2bf(s_pre * xv.w) << 16);
  *(uint2*)(preA + (long)t * 1024 + tid * 4) = make_uint2(lo, hi);

  if (tid < 16) {
    const float ar = a_res[0];
    float Mv = expf(ar * tot[8 + tid] * rinv + bias_res[tid]);
#pragma unroll
    for (int it = 0; it < 20; ++it) {
      float cs = Mv + __shfl_xor(Mv, 4);
      cs += __shfl_xor(cs, 8);
      Mv = Mv / (cs + 1e-8f);   // col normalize (axis=-2)
      float rs = Mv + __shfl_xor(Mv, 1);
      rs += __shfl_xor(rs, 2);
      Mv = Mv / (rs + 1e-8f);   // row normalize (axis=-1)
    }
    float rs = Mv + __shfl_xor(Mv, 1);
    rs += __shfl_xor(rs, 2);
    if ((tid & 3) == 0) scal[(long)t * 8 + (tid >> 2)] = rs;  // r_i
  }
  if (tid < 4) {
    const float apo = a_post[0];
    float hp = 2.f / (1.f + expf(-(apo * tot[4 + tid] * rinv + bias_post[tid])));
    scal[(long)t * 8 + 4 + tid] = hp;  // H_post
  }
}

// ---------------- bf16 MFMA GEMM: C(MxN) = A(MxK, row-major) * Bt(NxK)^T ----------------
// BM=BN=128, BK=64, 256 threads (4 waves, 2x2), each wave 4x4 of 16x16x32 MFMA.
// REGISTER-STAGED pipeline, K-loop manually unrolled x2 so both register sets
// and LDS buffer indices are COMPILE-TIME constants (R4's runtime-indexed
// ra[p][i] spilled the whole pipeline to scratch: WRITE_SIZE 65MB -> 1GB).
// One barrier per K-tile (safe with dbuf: barrier(k) transitively orders
// iter-k+2 overwrites after iter-k reads). Requires T = K/64 even (16 / 64 here).
// LDS layout: elem (m, kc16B) at u16 index m*64 + ((kc ^ (m&7))*8)
//   -> ds_write conflict-free, ds_read frag 2-way max (free), global coalesced.
// EPI: 0 = gelu -> bf16 dst (ld N) | 1 = build merged (ld 4096) | 2 = +bias+x -> fp32
template <int EPI>
__global__ __launch_bounds__(256) void gemm_bf16(const u16* __restrict__ A,
                                                 const u16* __restrict__ Bt,
                                                 const int K, const int N,
                                                 const float* __restrict__ bias,
                                                 const float* __restrict__ X,
                                                 const float* __restrict__ scal,
                                                 void* __restrict__ dstv) {
  __shared__ __attribute__((aligned(16))) u16 As[2][128 * 64];
  __shared__ __attribute__((aligned(16))) u16 Bs[2][128 * 64];
  const int tid = threadIdx.x;
  const int lane = tid & 63;
  const int wave = tid >> 6;
  const int wm = wave >> 1, wn = wave & 1;
  const long bm = (long)blockIdx.y * 128;
  const long bn = (long)blockIdx.x * 128;

  const int srow = lane >> 3;  // row within 8-row chunk
  const int skc = lane & 7;    // 16B chunk (lane-ordered -> coalesced global)

  const u16* Ag = A + (bm + wave * 32 + srow) * (long)K + skc * 8;
  const u16* Bg = Bt + (bn + wave * 32 + srow) * (long)K + skc * 8;
  const int lws = (wave * 32 + srow) * 64 + ((skc ^ srow) * 8);

  f32x4 acc[4][4] = {};
  uint4 ra0[4], rb0[4], ra1[4], rb1[4];

  const int T = K >> 6;  // even (16 or 64)

#pragma unroll
  for (int i = 0; i < 4; ++i) {
    ra0[i] = *(const uint4*)(Ag + (long)i * 8 * K);
    rb0[i] = *(const uint4*)(Bg + (long)i * 8 * K);
  }

  for (int kt = 0; kt < T; kt += 2) {
    // ---- phase 0: stage set0 -> buf0, prefetch tile kt+1 -> set1 ----
    {
      const long ko = (long)(kt + 1) * 64;
#pragma unroll
      for (int i = 0; i < 4; ++i) {
        ra1[i] = *(const uint4*)(Ag + (long)i * 8 * K + ko);
        rb1[i] = *(const uint4*)(Bg + (long)i * 8 * K + ko);
      }
    }
#pragma unroll
    for (int i = 0; i < 4; ++i) {
      *(uint4*)&As[0][lws + i * 512] = ra0[i];
      *(uint4*)&Bs[0][lws + i * 512] = rb0[i];
    }
    __syncthreads();
#pragma unroll
    for (int h2 = 0; h2 < 2; ++h2) {
      const int kc = h2 * 4 + (lane >> 4);
      bf16x8 af[4], bfr[4];
#pragma unroll
      for (int i = 0; i < 4; ++i) {
        const int m = wm * 64 + i * 16 + (lane & 15);
        af[i] = *(const bf16x8*)&As[0][m * 64 + ((kc ^ (m & 7)) * 8)];
        const int n = wn * 64 + i * 16 + (lane & 15);
        bfr[i] = *(const bf16x8*)&Bs[0][n * 64 + ((kc ^ (n & 7)) * 8)];
      }
#pragma unroll
      for (int i = 0; i < 4; ++i)
#pragma unroll
        for (int j = 0; j < 4; ++j)
          acc[i][j] = __builtin_amdgcn_mfma_f32_16x16x32_bf16(af[i], bfr[j], acc[i][j], 0, 0, 0);
    }
    // ---- phase 1: stage set1 -> buf1, prefetch tile kt+2 -> set0 ----
    if (kt + 2 < T) {
      const long ko = (long)(kt + 2) * 64;
#pragma unroll
      for (int i = 0; i < 4; ++i) {
        ra0[i] = *(const uint4*)(Ag + (long)i * 8 * K + ko);
        rb0[i] = *(const uint4*)(Bg + (long)i * 8 * K + ko);
      }
    }
#pragma unroll
    for (int i = 0; i < 4; ++i) {
      *(uint4*)&As[1][lws + i * 512] = ra1[i];
      *(uint4*)&Bs[1][lws + i * 512] = rb1[i];
    }
    __syncthreads();
#pragma unroll
    for (int h2 = 0; h2 < 2; ++h2) {
      const int kc = h2 * 4 + (lane >> 4);
      bf16x8 af[4], bfr[4];
#pragma unroll
      for (int i = 0; i < 4; ++i) {
        const int m = wm * 64 + i * 16 + (lane & 15);
        af[i] = *(const bf16x8*)&As[1][m * 64 + ((kc ^ (m & 7)) * 8)];
        const int n = wn * 64 + i * 16 + (lane & 15);
        bfr[i] = *(const bf16x8*)&Bs[1][n * 64 + ((kc ^ (n & 7)) * 8)];
      }
#pragma unroll
      for (int i = 0; i < 4; ++i)
#pragma unroll
        for (int j = 0; j < 4; ++j)
          acc[i][j] = __builtin_amdgcn_mfma_f32_16x16x32_bf16(af[i], bfr[j], acc[i][j], 0, 0, 0);
    }
    __syncthreads();  // protect buf0 from next-iter overwrite while readers finish
  }

  // Epilogue. C/D layout: col = lane&15, row = (lane>>4)*4 + reg  [verified m89/m91]
  if constexpr (EPI == 0) {
    u16* dst = (u16*)dstv;
#pragma unroll
    for (int i = 0; i < 4; ++i)
#pragma unroll
      for (int r = 0; r < 4; ++r) {
        const long row = bm + wm * 64 + i * 16 + (lane >> 4) * 4 + r;
#pragma unroll
        for (int j = 0; j < 4; ++j) {
          const long col = bn + wn * 64 + j * 16 + (lane & 15);
          float v = acc[i][j][r] + bias[col];
          float g = 0.5f * v * (1.0f + erff(v * 0.70710678118654752f));
          dst[row * N + col] = f2bf(g);
        }
      }
  } else if constexpr (EPI == 1) {
    u16* dst = (u16*)dstv;  // merged, ld 4096
#pragma unroll
    for (int i = 0; i < 4; ++i)
#pragma unroll
      for (int r = 0; r < 4; ++r) {
        const long row = bm + wm * 64 + i * 16 + (lane >> 4) * 4 + r;
        const float4 rv = *(const float4*)(scal + row * 8);
        const float4 hv = *(const float4*)(scal + row * 8 + 4);
#pragma unroll
        for (int j = 0; j < 4; ++j) {
          const long col = bn + wn * 64 + j * 16 + (lane & 15);
          const float f = acc[i][j][r] + bias[col];
          const float xval = X[row * 1024 + col];
          const long base = row * 4096 + col;
          dst[base] = f2bf(rv.x * xval + hv.x * f);
          dst[base + 1024] = f2bf(rv.y * xval + hv.y * f);
          dst[base + 2048] = f2bf(rv.z * xval + hv.z * f);
          dst[base + 3072] = f2bf(rv.w * xval + hv.w * f);
        }
      }
  } else {
    float* dst = (float*)dstv;
#pragma unroll
    for (int i = 0; i < 4; ++i)
#pragma unroll
      for (int r = 0; r < 4; ++r) {
        const long row = bm + wm * 64 + i * 16 + (lane >> 4) * 4 + r;
#pragma unroll
        for (int j = 0; j < 4; ++j) {
          const long col = bn + wn * 64 + j * 16 + (lane & 15);
          dst[row * 1024 + col] = acc[i][j][r] + bias[col] + X[row * 1024 + col];
        }
      }
  }
}

extern "C" void kernel_launch(void* const* d_in, const int* in_sizes, int n_in,
                              void* d_out, int out_size, void* d_ws, size_t ws_size,
                              hipStream_t stream) {
  (void)in_sizes; (void)n_in; (void)out_size; (void)ws_size;
  const float* x = (const float*)d_in[0];
  const float* rmsw = (const float*)d_in[1];
  const float* Wdyn = (const float*)d_in[2];
  const float* bias_pre = (const float*)d_in[3];
  const float* bias_post = (const float*)d_in[4];
  const float* bias_res = (const float*)d_in[5];
  const float* a_pre = (const float*)d_in[6];
  const float* a_post = (const float*)d_in[7];
  const float* a_res = (const float*)d_in[8];
  const float* W1 = (const float*)d_in[9];
  const float* b1 = (const float*)d_in[10];
  const float* W2 = (const float*)d_in[11];
  const float* b2 = (const float*)d_in[12];
  const float* Wout = (const float*)d_in[13];
  const float* bout = (const float*)d_in[14];
  float* out = (float*)d_out;
  char* ws = (char*)d_ws;

  constexpr size_t OFF_W1BT = 0;          // 4096x1024 bf16  (8 MiB)
  constexpr size_t OFF_W2BT = 8388608;    // 1024x4096 bf16  (8 MiB)
  constexpr size_t OFF_WOBT = 16777216;   // 1024x4096 bf16  (8 MiB)
  constexpr size_t OFF_WEFF = 25165824;   // 24x1024 f32     (96 KiB, transposed)
  constexpr size_t OFF_SCAL = 25264128;   // 8192x8 f32      (256 KiB)
  constexpr size_t OFF_H    = 25526272;   // 8192x4096 bf16  (64 MiB)
  constexpr size_t OFF_PREA = 92635136;   // 8192x1024 bf16  (16 MiB)
  constexpr size_t OFF_MERG = 92635136;   // 8192x4096 bf16  (64 MiB)

  u16* W1bt = (u16*)(ws + OFF_W1BT);
  u16* W2bt = (u16*)(ws + OFF_W2BT);
  u16* Wobt = (u16*)(ws + OFF_WOBT);
  float* WT = (float*)(ws + OFF_WEFF);
  float* scal = (float*)(ws + OFF_SCAL);
  u16* h = (u16*)(ws + OFF_H);
  u16* preA = (u16*)(ws + OFF_PREA);
  u16* merged = (u16*)(ws + OFF_MERG);

  weff_kernel<<<96, 256, 0, stream>>>(rmsw, Wdyn, WT);
  transpose_kernel<<<dim3(128, 32), 256, 0, stream>>>(W1, W1bt, 1024, 4096);
  transpose_kernel<<<dim3(32, 128), 256, 0, stream>>>(W2, W2bt, 4096, 1024);
  transpose_kernel<<<dim3(32, 128), 256, 0, stream>>>(Wout, Wobt, 4096, 1024);
  prep_tokens<<<8192, 256, 0, stream>>>(x, WT, bias_pre, bias_post, bias_res,
                                        a_pre, a_post, a_res, preA, scal);
  // h = gelu(preA @ W1 + b1)                      M=8192 N=4096 K=1024
  gemm_bf16<0><<<dim3(32, 64), 256, 0, stream>>>(preA, W1bt, 1024, 4096, b1, nullptr, nullptr, h);
  // merged[:, s*1024+c] = r_s*x + hp_s*(h @ W2 + b2)   M=8192 N=1024 K=4096
  gemm_bf16<1><<<dim3(8, 64), 256, 0, stream>>>(h, W2bt, 4096, 1024, b2, x, scal, merged);
  // out = merged @ Wout + bout + x                M=8192 N=1024 K=4096
  gemm_bf16<2><<<dim3(8, 64), 256, 0, stream>>>(merged, Wobt, 4096, 1024, bout, x, nullptr, out);
}

// Round 6
// 580.798 us; speedup vs baseline: 2.1363x; 1.8144x over previous
//
#include <hip/hip_runtime.h>

typedef unsigned short u16;
typedef __bf16 bf16x8 __attribute__((ext_vector_type(8)));
typedef float f32x4 __attribute__((ext_vector_type(4)));

typedef __attribute__((address_space(1))) void gvoid;
typedef __attribute__((address_space(3))) void lvoid;

__device__ __forceinline__ u16 f2bf(float f) {
  unsigned int u = __builtin_bit_cast(unsigned int, f);
  u += 0x7fffu + ((u >> 16) & 1u);
  return (u16)(u >> 16);
}

__device__ __forceinline__ void gl_lds16(const u16* g, u16* l) {
  // async global->LDS, 16B per lane; LDS dest = wave-uniform base + lane*16
  __builtin_amdgcn_global_load_lds((gvoid*)(g), (lvoid*)(l), 16, 0, 0);
}

// ---------------- WT[j][c] = sum_s rmsw[s*1024+c] * Wdyn[(s*1024+c)*24 + j] ------------
__global__ __launch_bounds__(256) void weff_kernel(const float* __restrict__ rmsw,
                                                   const float* __restrict__ Wdyn,
                                                   float* __restrict__ WT) {
  int idx = blockIdx.x * 256 + threadIdx.x;  // 24576 threads
  int j = idx >> 10, c = idx & 1023;
  float s = 0.f;
#pragma unroll
  for (int st = 0; st < 4; ++st) {
    int r = st * 1024 + c;
    s += rmsw[r] * Wdyn[(long)r * 24 + j];
  }
  WT[idx] = s;
}

// ---------------- transpose fp32 (R x C) -> bf16 (C x R) --------------------------------
__global__ __launch_bounds__(256) void transpose_kernel(const float* __restrict__ src,
                                                        u16* __restrict__ dst,
                                                        int R, int C) {
  __shared__ float tile[32][33];
  int tx = threadIdx.x & 31, ty = threadIdx.x >> 5;  // 32 x 8
  long c0 = (long)blockIdx.x * 32, r0 = (long)blockIdx.y * 32;
#pragma unroll
  for (int k = 0; k < 4; ++k)
    tile[ty + 8 * k][tx] = src[(r0 + ty + 8 * k) * C + c0 + tx];
  __syncthreads();
#pragma unroll
  for (int k = 0; k < 4; ++k)
    dst[(c0 + ty + 8 * k) * R + r0 + tx] = f2bf(tile[tx][ty + 8 * k]);
}

// ---------------- per-token prep: rms, dynamic(24), gates, sinkhorn, preA ---------------
__global__ __launch_bounds__(256) void prep_tokens(
    const float* __restrict__ x, const float* __restrict__ WT,
    const float* __restrict__ bias_pre, const float* __restrict__ bias_post,
    const float* __restrict__ bias_res, const float* __restrict__ a_pre,
    const float* __restrict__ a_post, const float* __restrict__ a_res,
    u16* __restrict__ preA, float* __restrict__ scal) {
  const int t = blockIdx.x;
  const int tid = threadIdx.x;
  const float4 xv = *(const float4*)(x + (long)t * 1024 + tid * 4);
  float ssq = xv.x * xv.x + xv.y * xv.y + xv.z * xv.z + xv.w * xv.w;
  float raw[24];
#pragma unroll
  for (int j = 0; j < 24; ++j) {
    const float4 w = *(const float4*)(WT + (long)j * 1024 + tid * 4);
    raw[j] = xv.x * w.x + xv.y * w.y + xv.z * w.z + xv.w * w.w;
  }
#pragma unroll
  for (int m = 1; m < 64; m <<= 1) {
    ssq += __shfl_xor(ssq, m);
#pragma unroll
    for (int j = 0; j < 24; ++j) raw[j] += __shfl_xor(raw[j], m);
  }
  __shared__ float red[4][25];
  __shared__ float tot[25];
  const int lane = tid & 63, wv = tid >> 6;
  if (lane == 0) {
#pragma unroll
    for (int j = 0; j < 24; ++j) red[wv][j] = raw[j];
    red[wv][24] = ssq;
  }
  __syncthreads();
  if (tid < 25) tot[tid] = red[0][tid] + red[1][tid] + red[2][tid] + red[3][tid];
  __syncthreads();

  const float rms = sqrtf(tot[24] * (1.0f / 1024.0f) + 1e-8f);
  const float rinv = 1.0f / rms;

  const float ap = a_pre[0];
  float s_pre = 0.f;
#pragma unroll
  for (int i = 0; i < 4; ++i)
    s_pre += 1.f / (1.f + expf(-(ap * tot[i] * rinv + bias_pre[i])));

  unsigned int lo = (unsigned)f2bf(s_pre * xv.x) | ((unsigned)f2bf(s_pre * xv.y) << 16);
  unsigned int hi = (unsigned)f2bf(s_pre * xv.z) | ((unsigned)f2bf(s_pre * xv.w) << 16);
  *(uint2*)(preA + (long)t * 1024 + tid * 4) = make_uint2(lo, hi);

  if (tid < 16) {
    const float ar = a_res[0];
    float Mv = expf(ar * tot[8 + tid] * rinv + bias_res[tid]);
#pragma unroll
    for (int it = 0; it < 20; ++it) {
      float cs = Mv + __shfl_xor(Mv, 4);
      cs += __shfl_xor(cs, 8);
      Mv = Mv / (cs + 1e-8f);   // col normalize (axis=-2)
      float rs = Mv + __shfl_xor(Mv, 1);
      rs += __shfl_xor(rs, 2);
      Mv = Mv / (rs + 1e-8f);   // row normalize (axis=-1)
    }
    float rs = Mv + __shfl_xor(Mv, 1);
    rs += __shfl_xor(rs, 2);
    if ((tid & 3) == 0) scal[(long)t * 8 + (tid >> 2)] = rs;  // r_i
  }
  if (tid < 4) {
    const float apo = a_post[0];
    float hp = 2.f / (1.f + expf(-(apo * tot[4 + tid] * rinv + bias_post[tid])));
    scal[(long)t * 8 + 4 + tid] = hp;  // H_post
  }
}

// ---------------- bf16 MFMA GEMM (R3 core): C = A(M x lda) * Bt(N x lda)^T --------------
// BM=BN=128, BK=64, 256 threads (4 waves, 2x2), each wave 4x4 of 16x16x32 MFMA.
// gl_lds staging, lane-ordered (measured best: R3, 153us). Supports split-K via
// blockIdx.z: this block handles K range [z*Klen, (z+1)*Klen).
// LDS: 8-row groups of 512 u16, stride 520 (16B pad) -> 8-way ds_read conflict, survivable.
// EPI: 0 = gelu -> bf16 dst (ld N) | 3 = raw fp32 partial -> P + z*8192*1024
template <int EPI>
__global__ __launch_bounds__(256) void gemm_bf16(const u16* __restrict__ A,
                                                 const u16* __restrict__ Bt,
                                                 const int lda, const int Klen,
                                                 const int N,
                                                 const float* __restrict__ bias,
                                                 void* __restrict__ dstv) {
  __shared__ __attribute__((aligned(16))) u16 As[16 * 520];
  __shared__ __attribute__((aligned(16))) u16 Bs[16 * 520];
  const int tid = threadIdx.x;
  const int lane = tid & 63;
  const int wave = tid >> 6;
  const int wm = wave >> 1, wn = wave & 1;
  const long bm = (long)blockIdx.y * 128;
  const long bn = (long)blockIdx.x * 128;
  const long koff = (long)blockIdx.z * Klen;

  const int srow = lane >> 3;  // row within 8-row chunk
  const int skc = lane & 7;    // chunk (lane-ordered -> coalesced)

  const u16* Ag = A + (bm + wave * 32 + srow) * (long)lda + koff + skc * 8;
  const u16* Bg = Bt + (bn + wave * 32 + srow) * (long)lda + koff + skc * 8;

  f32x4 acc[4][4] = {};

  for (int kt = 0; kt < Klen; kt += 64) {
#pragma unroll
    for (int i = 0; i < 4; ++i) {
      gl_lds16(Ag + (long)i * 8 * lda + kt, &As[(wave * 4 + i) * 520]);
      gl_lds16(Bg + (long)i * 8 * lda + kt, &Bs[(wave * 4 + i) * 520]);
    }
    __syncthreads();
#pragma unroll
    for (int h2 = 0; h2 < 2; ++h2) {
      const int kc = h2 * 4 + (lane >> 4);
      bf16x8 af[4], bfr[4];
#pragma unroll
      for (int i = 0; i < 4; ++i) {
        const int m = wm * 64 + i * 16 + (lane & 15);
        af[i] = *(const bf16x8*)&As[(m >> 3) * 520 + (m & 7) * 64 + kc * 8];
        const int n = wn * 64 + i * 16 + (lane & 15);
        bfr[i] = *(const bf16x8*)&Bs[(n >> 3) * 520 + (n & 7) * 64 + kc * 8];
      }
#pragma unroll
      for (int i = 0; i < 4; ++i)
#pragma unroll
        for (int j = 0; j < 4; ++j)
          acc[i][j] = __builtin_amdgcn_mfma_f32_16x16x32_bf16(af[i], bfr[j], acc[i][j], 0, 0, 0);
    }
    __syncthreads();
  }

  // Epilogue. C/D layout: col = lane&15, row = (lane>>4)*4 + reg  [verified m89/m91]
  if constexpr (EPI == 0) {
    u16* dst = (u16*)dstv;
#pragma unroll
    for (int i = 0; i < 4; ++i)
#pragma unroll
      for (int r = 0; r < 4; ++r) {
        const long row = bm + wm * 64 + i * 16 + (lane >> 4) * 4 + r;
#pragma unroll
        for (int j = 0; j < 4; ++j) {
          const long col = bn + wn * 64 + j * 16 + (lane & 15);
          float v = acc[i][j][r] + bias[col];
          float g = 0.5f * v * (1.0f + erff(v * 0.70710678118654752f));
          dst[row * N + col] = f2bf(g);
        }
      }
  } else {
    float* dst = (float*)dstv + (long)blockIdx.z * 8192 * 1024;
#pragma unroll
    for (int i = 0; i < 4; ++i)
#pragma unroll
      for (int r = 0; r < 4; ++r) {
        const long row = bm + wm * 64 + i * 16 + (lane >> 4) * 4 + r;
#pragma unroll
        for (int j = 0; j < 4; ++j) {
          const long col = bn + wn * 64 + j * 16 + (lane & 15);
          dst[row * N + col] = acc[i][j][r];
        }
      }
  }
}

// ---------------- combine2: merged[t, s*1024+c] = r_s*x[t,c] + hp_s*(P0+P1+b2)[t,c] ----
__global__ __launch_bounds__(256) void combine2_kernel(const float* __restrict__ P,
                                                       const float* __restrict__ x,
                                                       const float* __restrict__ b2,
                                                       const float* __restrict__ scal,
                                                       u16* __restrict__ merged) {
  const long idx = (long)blockIdx.x * 256 + threadIdx.x;  // 8192*256
  const long t = idx >> 8;
  const int c = (int)(idx & 255) * 4;
  const float4 p0 = *(const float4*)(P + t * 1024 + c);
  const float4 p1 = *(const float4*)(P + 8192L * 1024 + t * 1024 + c);
  const float4 xv = *(const float4*)(x + t * 1024 + c);
  const float4 bv = *(const float4*)(b2 + c);
  const float f0 = p0.x + p1.x + bv.x, f1 = p0.y + p1.y + bv.y;
  const float f2 = p0.z + p1.z + bv.z, f3 = p0.w + p1.w + bv.w;
  const float4 rv = *(const float4*)(scal + t * 8);
  const float4 hv = *(const float4*)(scal + t * 8 + 4);
  const float rr[4] = {rv.x, rv.y, rv.z, rv.w};
  const float hh[4] = {hv.x, hv.y, hv.z, hv.w};
#pragma unroll
  for (int s = 0; s < 4; ++s) {
    unsigned int lo = (unsigned)f2bf(rr[s] * xv.x + hh[s] * f0) |
                      ((unsigned)f2bf(rr[s] * xv.y + hh[s] * f1) << 16);
    unsigned int hi = (unsigned)f2bf(rr[s] * xv.z + hh[s] * f2) |
                      ((unsigned)f2bf(rr[s] * xv.w + hh[s] * f3) << 16);
    *(uint2*)(merged + t * 4096 + s * 1024 + c) = make_uint2(lo, hi);
  }
}

// ---------------- combine3: out[t,c] = P0+P1+bout[c]+x[t,c] ----------------------------
__global__ __launch_bounds__(256) void combine3_kernel(const float* __restrict__ P,
                                                       const float* __restrict__ x,
                                                       const float* __restrict__ bout,
                                                       float* __restrict__ out) {
  const long idx = (long)blockIdx.x * 256 + threadIdx.x;
  const long t = idx >> 8;
  const int c = (int)(idx & 255) * 4;
  const float4 p0 = *(const float4*)(P + t * 1024 + c);
  const float4 p1 = *(const float4*)(P + 8192L * 1024 + t * 1024 + c);
  const float4 xv = *(const float4*)(x + t * 1024 + c);
  const float4 bv = *(const float4*)(bout + c);
  float4 o;
  o.x = p0.x + p1.x + bv.x + xv.x;
  o.y = p0.y + p1.y + bv.y + xv.y;
  o.z = p0.z + p1.z + bv.z + xv.z;
  o.w = p0.w + p1.w + bv.w + xv.w;
  *(float4*)(out + t * 1024 + c) = o;
}

extern "C" void kernel_launch(void* const* d_in, const int* in_sizes, int n_in,
                              void* d_out, int out_size, void* d_ws, size_t ws_size,
                              hipStream_t stream) {
  (void)in_sizes; (void)n_in; (void)out_size; (void)ws_size;
  const float* x = (const float*)d_in[0];
  const float* rmsw = (const float*)d_in[1];
  const float* Wdyn = (const float*)d_in[2];
  const float* bias_pre = (const float*)d_in[3];
  const float* bias_post = (const float*)d_in[4];
  const float* bias_res = (const float*)d_in[5];
  const float* a_pre = (const float*)d_in[6];
  const float* a_post = (const float*)d_in[7];
  const float* a_res = (const float*)d_in[8];
  const float* W1 = (const float*)d_in[9];
  const float* b1 = (const float*)d_in[10];
  const float* W2 = (const float*)d_in[11];
  const float* b2 = (const float*)d_in[12];
  const float* Wout = (const float*)d_in[13];
  const float* bout = (const float*)d_in[14];
  float* out = (float*)d_out;
  char* ws = (char*)d_ws;

  // ws layout (MiB):  [0,8) W1bt | [8,16) W2bt | [16,24) Wobt | [24,25) WT+scal
  //   [25,89)  h (bf16, GEMM1 out)  -> later ALIASED by merged (h dead after GEMM2 K-loops)
  //   [89,153) P (2x 8192x1024 fp32 partials) -> initially ALIASED by preA (dead after GEMM1)
  constexpr size_t MB = 1048576;
  u16* W1bt = (u16*)(ws);
  u16* W2bt = (u16*)(ws + 8 * MB);
  u16* Wobt = (u16*)(ws + 16 * MB);
  float* WT = (float*)(ws + 24 * MB);
  float* scal = (float*)(ws + 24 * MB + 98304);
  u16* h = (u16*)(ws + 25 * MB);
  u16* merged = (u16*)(ws + 25 * MB);   // aliases h
  float* P = (float*)(ws + 89 * MB);
  u16* preA = (u16*)(ws + 89 * MB);     // aliases P

  weff_kernel<<<96, 256, 0, stream>>>(rmsw, Wdyn, WT);
  transpose_kernel<<<dim3(128, 32), 256, 0, stream>>>(W1, W1bt, 1024, 4096);
  transpose_kernel<<<dim3(32, 128), 256, 0, stream>>>(W2, W2bt, 4096, 1024);
  transpose_kernel<<<dim3(32, 128), 256, 0, stream>>>(Wout, Wobt, 4096, 1024);
  prep_tokens<<<8192, 256, 0, stream>>>(x, WT, bias_pre, bias_post, bias_res,
                                        a_pre, a_post, a_res, preA, scal);
  // GEMM1: h = gelu(preA @ W1 + b1)        M=8192 N=4096 K=1024 (no split)
  gemm_bf16<0><<<dim3(32, 64, 1), 256, 0, stream>>>(preA, W1bt, 1024, 1024, 4096, b1, h);
  // GEMM2 (split-K x2): P[z] = h @ W2 half-K partials   M=8192 N=1024 K=4096
  gemm_bf16<3><<<dim3(8, 64, 2), 256, 0, stream>>>(h, W2bt, 4096, 2048, 1024, nullptr, P);
  combine2_kernel<<<8192, 256, 0, stream>>>(P, x, b2, scal, merged);
  // GEMM3 (split-K x2): P[z] = merged @ Wout half-K partials   M=8192 N=1024 K=4096
  gemm_bf16<3><<<dim3(8, 64, 2), 256, 0, stream>>>(merged, Wobt, 4096, 2048, 1024, nullptr, P);
  combine3_kernel<<<8192, 256, 0, stream>>>(P, x, bout, out);
}

// Round 7
// 562.406 us; speedup vs baseline: 2.2061x; 1.0327x over previous
//
#include <hip/hip_runtime.h>

typedef unsigned short u16;
typedef __bf16 bf16x8 __attribute__((ext_vector_type(8)));
typedef float f32x4 __attribute__((ext_vector_type(4)));

__device__ __forceinline__ u16 f2bf(float f) {
  unsigned int u = __builtin_bit_cast(unsigned int, f);
  u += 0x7fffu + ((u >> 16) & 1u);
  return (u16)(u >> 16);
}

// lgkm-only barrier: waits ds_write/ds_read completion, leaves global loads in
// flight (0xc07f = vmcnt(63) expcnt(7) lgkmcnt(0) on gfx9 encoding).
// sched_barrier(0) pins LDS ops on the correct side of the s_barrier.
__device__ __forceinline__ void lds_barrier() {
  __builtin_amdgcn_sched_barrier(0);
  __builtin_amdgcn_s_waitcnt(0xc07f);
  __builtin_amdgcn_s_barrier();
  __builtin_amdgcn_sched_barrier(0);
}

// ---------------- WT[j][c] = sum_s rmsw[s*1024+c] * Wdyn[(s*1024+c)*24 + j] ------------
__global__ __launch_bounds__(256) void weff_kernel(const float* __restrict__ rmsw,
                                                   const float* __restrict__ Wdyn,
                                                   float* __restrict__ WT) {
  int idx = blockIdx.x * 256 + threadIdx.x;  // 24576 threads
  int j = idx >> 10, c = idx & 1023;
  float s = 0.f;
#pragma unroll
  for (int st = 0; st < 4; ++st) {
    int r = st * 1024 + c;
    s += rmsw[r] * Wdyn[(long)r * 24 + j];
  }
  WT[idx] = s;
}

// ---------------- transpose fp32 (R x C) -> bf16 (C x R) --------------------------------
__global__ __launch_bounds__(256) void transpose_kernel(const float* __restrict__ src,
                                                        u16* __restrict__ dst,
                                                        int R, int C) {
  __shared__ float tile[32][33];
  int tx = threadIdx.x & 31, ty = threadIdx.x >> 5;  // 32 x 8
  long c0 = (long)blockIdx.x * 32, r0 = (long)blockIdx.y * 32;
#pragma unroll
  for (int k = 0; k < 4; ++k)
    tile[ty + 8 * k][tx] = src[(r0 + ty + 8 * k) * C + c0 + tx];
  __syncthreads();
#pragma unroll
  for (int k = 0; k < 4; ++k)
    dst[(c0 + ty + 8 * k) * R + r0 + tx] = f2bf(tile[tx][ty + 8 * k]);
}

// ---------------- per-token prep: rms, dynamic(24), gates, sinkhorn, preA ---------------
__global__ __launch_bounds__(256) void prep_tokens(
    const float* __restrict__ x, const float* __restrict__ WT,
    const float* __restrict__ bias_pre, const float* __restrict__ bias_post,
    const float* __restrict__ bias_res, const float* __restrict__ a_pre,
    const float* __restrict__ a_post, const float* __restrict__ a_res,
    u16* __restrict__ preA, float* __restrict__ scal) {
  const int t = blockIdx.x;
  const int tid = threadIdx.x;
  const float4 xv = *(const float4*)(x + (long)t * 1024 + tid * 4);
  float ssq = xv.x * xv.x + xv.y * xv.y + xv.z * xv.z + xv.w * xv.w;
  float raw[24];
#pragma unroll
  for (int j = 0; j < 24; ++j) {
    const float4 w = *(const float4*)(WT + (long)j * 1024 + tid * 4);
    raw[j] = xv.x * w.x + xv.y * w.y + xv.z * w.z + xv.w * w.w;
  }
#pragma unroll
  for (int m = 1; m < 64; m <<= 1) {
    ssq += __shfl_xor(ssq, m);
#pragma unroll
    for (int j = 0; j < 24; ++j) raw[j] += __shfl_xor(raw[j], m);
  }
  __shared__ float red[4][25];
  __shared__ float tot[25];
  const int lane = tid & 63, wv = tid >> 6;
  if (lane == 0) {
#pragma unroll
    for (int j = 0; j < 24; ++j) red[wv][j] = raw[j];
    red[wv][24] = ssq;
  }
  __syncthreads();
  if (tid < 25) tot[tid] = red[0][tid] + red[1][tid] + red[2][tid] + red[3][tid];
  __syncthreads();

  const float rms = sqrtf(tot[24] * (1.0f / 1024.0f) + 1e-8f);
  const float rinv = 1.0f / rms;

  const float ap = a_pre[0];
  float s_pre = 0.f;
#pragma unroll
  for (int i = 0; i < 4; ++i)
    s_pre += 1.f / (1.f + expf(-(ap * tot[i] * rinv + bias_pre[i])));

  unsigned int lo = (unsigned)f2bf(s_pre * xv.x) | ((unsigned)f2bf(s_pre * xv.y) << 16);
  unsigned int hi = (unsigned)f2bf(s_pre * xv.z) | ((unsigned)f2bf(s_pre * xv.w) << 16);
  *(uint2*)(preA + (long)t * 1024 + tid * 4) = make_uint2(lo, hi);

  if (tid < 16) {
    const float ar = a_res[0];
    float Mv = expf(ar * tot[8 + tid] * rinv + bias_res[tid]);
#pragma unroll
    for (int it = 0; it < 20; ++it) {
      float cs = Mv + __shfl_xor(Mv, 4);
      cs += __shfl_xor(cs, 8);
      Mv = Mv / (cs + 1e-8f);   // col normalize (axis=-2)
      float rs = Mv + __shfl_xor(Mv, 1);
      rs += __shfl_xor(rs, 2);
      Mv = Mv / (rs + 1e-8f);   // row normalize (axis=-1)
    }
    float rs = Mv + __shfl_xor(Mv, 1);
    rs += __shfl_xor(rs, 2);
    if ((tid & 3) == 0) scal[(long)t * 8 + (tid >> 2)] = rs;  // r_i
  }
  if (tid < 4) {
    const float apo = a_post[0];
    float hp = 2.f / (1.f + expf(-(apo * tot[4 + tid] * rinv + bias_post[tid])));
    scal[(long)t * 8 + 4 + tid] = hp;  // H_post
  }
}

// ---------------- bf16 MFMA GEMM, pipelined K-loop: C = A(M x lda) * Bt(N x lda)^T ------
// BM=BN=128, BK=32, 256 threads (4 waves 2x2), wave tile 64x64 = 4x4 of 16x16x32 MFMA.
// Per tile: ds_write regs->buf[q] (tile k) | issue global loads tile k+1 -> regs |
// lgkm-ONLY barrier (global loads stay in flight across it; their only wait is the
// compiler's fine-grained vmcnt before next tile's ds_write) | compute buf[q].
// One barrier/tile. Single staging reg set, compile-time buffer indices (unroll x2).
// Safety: a wave's buf[q] frag reads complete before it passes the NEXT phase's
// lgkmcnt(0)+barrier, so the following overwrite of buf[q] is ordered after all reads.
// LDS row stride 64B: ds_write / ds_read_b128 patterns both tile the 8 bank-groups evenly.
// EPI: 0 = gelu -> bf16 dst (ld N) | 3 = raw fp32 partial -> dst + z*8192*1024
template <int EPI>
__global__ __launch_bounds__(256) void gemm_bf16(const u16* __restrict__ A,
                                                 const u16* __restrict__ Bt,
                                                 const int lda, const int Klen,
                                                 const int N,
                                                 const float* __restrict__ bias,
                                                 void* __restrict__ dstv) {
  __shared__ __attribute__((aligned(16))) u16 As[2][128 * 32];
  __shared__ __attribute__((aligned(16))) u16 Bs[2][128 * 32];
  const int tid = threadIdx.x;
  const int lane = tid & 63;
  const int wave = tid >> 6;
  const int wm = wave >> 1, wn = wave & 1;
  const long bm = (long)blockIdx.y * 128;
  const long bn = (long)blockIdx.x * 128;
  const long koff = (long)blockIdx.z * Klen;

  // staging: thread t -> rows (t>>2) and (t>>2)+64, 16B chunk t&3 (coalesced 64B/row/4lanes)
  const int r0 = tid >> 2;
  const int ch = tid & 3;
  const u16* Ag = A + (bm + r0) * (long)lda + koff + ch * 8;
  const u16* Bg = Bt + (bn + r0) * (long)lda + koff + ch * 8;
  const long rstep = 64L * lda;
  const int wof = r0 * 32 + ch * 8;  // u16 idx in buf; +64 rows -> +2048

  f32x4 acc[4][4] = {};
  uint4 rA0, rA1, rB0, rB1;

  const int T = Klen >> 5;  // 32 or 64 (even)

  // prologue: tile 0 -> regs
  rA0 = *(const uint4*)(Ag);
  rA1 = *(const uint4*)(Ag + rstep);
  rB0 = *(const uint4*)(Bg);
  rB1 = *(const uint4*)(Bg + rstep);

  for (int kt = 0; kt < T; kt += 2) {
    // ---- phase 0: buf0 <- tile kt, prefetch kt+1 ----
    *(uint4*)&As[0][wof] = rA0;
    *(uint4*)&As[0][wof + 2048] = rA1;
    *(uint4*)&Bs[0][wof] = rB0;
    *(uint4*)&Bs[0][wof + 2048] = rB1;
    {
      const long ko = (long)(kt + 1) * 32;  // kt+1 <= T-1 always (T even)
      rA0 = *(const uint4*)(Ag + ko);
      rA1 = *(const uint4*)(Ag + rstep + ko);
      rB0 = *(const uint4*)(Bg + ko);
      rB1 = *(const uint4*)(Bg + rstep + ko);
    }
    lds_barrier();
    {
      bf16x8 af[4], bfr[4];
      const int kc = (lane >> 4) * 8;
#pragma unroll
      for (int i = 0; i < 4; ++i) {
        const int m = wm * 64 + i * 16 + (lane & 15);
        af[i] = *(const bf16x8*)&As[0][m * 32 + kc];
        const int n = wn * 64 + i * 16 + (lane & 15);
        bfr[i] = *(const bf16x8*)&Bs[0][n * 32 + kc];
      }
#pragma unroll
      for (int i = 0; i < 4; ++i)
#pragma unroll
        for (int j = 0; j < 4; ++j)
          acc[i][j] = __builtin_amdgcn_mfma_f32_16x16x32_bf16(af[i], bfr[j], acc[i][j], 0, 0, 0);
    }
    // ---- phase 1: buf1 <- tile kt+1, prefetch kt+2 ----
    *(uint4*)&As[1][wof] = rA0;
    *(uint4*)&As[1][wof + 2048] = rA1;
    *(uint4*)&Bs[1][wof] = rB0;
    *(uint4*)&Bs[1][wof + 2048] = rB1;
    if (kt + 2 < T) {
      const long ko = (long)(kt + 2) * 32;
      rA0 = *(const uint4*)(Ag + ko);
      rA1 = *(const uint4*)(Ag + rstep + ko);
      rB0 = *(const uint4*)(Bg + ko);
      rB1 = *(const uint4*)(Bg + rstep + ko);
    }
    lds_barrier();
    {
      bf16x8 af[4], bfr[4];
      const int kc = (lane >> 4) * 8;
#pragma unroll
      for (int i = 0; i < 4; ++i) {
        const int m = wm * 64 + i * 16 + (lane & 15);
        af[i] = *(const bf16x8*)&As[1][m * 32 + kc];
        const int n = wn * 64 + i * 16 + (lane & 15);
        bfr[i] = *(const bf16x8*)&Bs[1][n * 32 + kc];
      }
#pragma unroll
      for (int i = 0; i < 4; ++i)
#pragma unroll
        for (int j = 0; j < 4; ++j)
          acc[i][j] = __builtin_amdgcn_mfma_f32_16x16x32_bf16(af[i], bfr[j], acc[i][j], 0, 0, 0);
    }
    // next phase-0 overwrite of buf0 is ordered after all waves' buf0 reads by the
    // phase-1 lgkmcnt(0)+barrier above.
  }

  // Epilogue. C/D layout: col = lane&15, row = (lane>>4)*4 + reg  [verified m89/m91]
  if constexpr (EPI == 0) {
    u16* dst = (u16*)dstv;
#pragma unroll
    for (int i = 0; i < 4; ++i)
#pragma unroll
      for (int r = 0; r < 4; ++r) {
        const long row = bm + wm * 64 + i * 16 + (lane >> 4) * 4 + r;
#pragma unroll
        for (int j = 0; j < 4; ++j) {
          const long col = bn + wn * 64 + j * 16 + (lane & 15);
          float v = acc[i][j][r] + bias[col];
          float g = 0.5f * v * (1.0f + erff(v * 0.70710678118654752f));
          dst[row * N + col] = f2bf(g);
        }
      }
  } else {
    float* dst = (float*)dstv + (long)blockIdx.z * 8192 * 1024;
#pragma unroll
    for (int i = 0; i < 4; ++i)
#pragma unroll
      for (int r = 0; r < 4; ++r) {
        const long row = bm + wm * 64 + i * 16 + (lane >> 4) * 4 + r;
#pragma unroll
        for (int j = 0; j < 4; ++j) {
          const long col = bn + wn * 64 + j * 16 + (lane & 15);
          dst[row * N + col] = acc[i][j][r];
        }
      }
  }
}

// ---------------- combine2: merged[t, s*1024+c] = r_s*x[t,c] + hp_s*(P0+P1+b2)[t,c] ----
__global__ __launch_bounds__(256) void combine2_kernel(const float* __restrict__ P,
                                                       const float* __restrict__ x,
                                                       const float* __restrict__ b2,
                                                       const float* __restrict__ scal,
                                                       u16* __restrict__ merged) {
  const long idx = (long)blockIdx.x * 256 + threadIdx.x;  // 8192*256
  const long t = idx >> 8;
  const int c = (int)(idx & 255) * 4;
  const float4 p0 = *(const float4*)(P + t * 1024 + c);
  const float4 p1 = *(const float4*)(P + 8192L * 1024 + t * 1024 + c);
  const float4 xv = *(const float4*)(x + t * 1024 + c);
  const float4 bv = *(const float4*)(b2 + c);
  const float f0 = p0.x + p1.x + bv.x, f1 = p0.y + p1.y + bv.y;
  const float f2 = p0.z + p1.z + bv.z, f3 = p0.w + p1.w + bv.w;
  const float4 rv = *(const float4*)(scal + t * 8);
  const float4 hv = *(const float4*)(scal + t * 8 + 4);
  const float rr[4] = {rv.x, rv.y, rv.z, rv.w};
  const float hh[4] = {hv.x, hv.y, hv.z, hv.w};
#pragma unroll
  for (int s = 0; s < 4; ++s) {
    unsigned int lo = (unsigned)f2bf(rr[s] * xv.x + hh[s] * f0) |
                      ((unsigned)f2bf(rr[s] * xv.y + hh[s] * f1) << 16);
    unsigned int hi = (unsigned)f2bf(rr[s] * xv.z + hh[s] * f2) |
                      ((unsigned)f2bf(rr[s] * xv.w + hh[s] * f3) << 16);
    *(uint2*)(merged + t * 4096 + s * 1024 + c) = make_uint2(lo, hi);
  }
}

// ---------------- combine3: out[t,c] = P0+P1+bout[c]+x[t,c] ----------------------------
__global__ __launch_bounds__(256) void combine3_kernel(const float* __restrict__ P,
                                                       const float* __restrict__ x,
                                                       const float* __restrict__ bout,
                                                       float* __restrict__ out) {
  const long idx = (long)blockIdx.x * 256 + threadIdx.x;
  const long t = idx >> 8;
  const int c = (int)(idx & 255) * 4;
  const float4 p0 = *(const float4*)(P + t * 1024 + c);
  const float4 p1 = *(const float4*)(P + 8192L * 1024 + t * 1024 + c);
  const float4 xv = *(const float4*)(x + t * 1024 + c);
  const float4 bv = *(const float4*)(bout + c);
  float4 o;
  o.x = p0.x + p1.x + bv.x + xv.x;
  o.y = p0.y + p1.y + bv.y + xv.y;
  o.z = p0.z + p1.z + bv.z + xv.z;
  o.w = p0.w + p1.w + bv.w + xv.w;
  *(float4*)(out + t * 1024 + c) = o;
}

extern "C" void kernel_launch(void* const* d_in, const int* in_sizes, int n_in,
                              void* d_out, int out_size, void* d_ws, size_t ws_size,
                              hipStream_t stream) {
  (void)in_sizes; (void)n_in; (void)out_size; (void)ws_size;
  const float* x = (const float*)d_in[0];
  const float* rmsw = (const float*)d_in[1];
  const float* Wdyn = (const float*)d_in[2];
  const float* bias_pre = (const float*)d_in[3];
  const float* bias_post = (const float*)d_in[4];
  const float* bias_res = (const float*)d_in[5];
  const float* a_pre = (const float*)d_in[6];
  const float* a_post = (const float*)d_in[7];
  const float* a_res = (const float*)d_in[8];
  const float* W1 = (const float*)d_in[9];
  const float* b1 = (const float*)d_in[10];
  const float* W2 = (const float*)d_in[11];
  const float* b2 = (const float*)d_in[12];
  const float* Wout = (const float*)d_in[13];
  const float* bout = (const float*)d_in[14];
  float* out = (float*)d_out;
  char* ws = (char*)d_ws;

  // ws layout (MiB):  [0,8) W1bt | [8,16) W2bt | [16,24) Wobt | [24,25) WT+scal
  //   [25,89)  h (bf16) -> later ALIASED by merged (h dead after GEMM2 K-loops)
  //   [89,153) P (2x 8192x1024 fp32 partials) -> initially ALIASED by preA (dead after GEMM1)
  constexpr size_t MB = 1048576;
  u16* W1bt = (u16*)(ws);
  u16* W2bt = (u16*)(ws + 8 * MB);
  u16* Wobt = (u16*)(ws + 16 * MB);
  float* WT = (float*)(ws + 24 * MB);
  float* scal = (float*)(ws + 24 * MB + 98304);
  u16* h = (u16*)(ws + 25 * MB);
  u16* merged = (u16*)(ws + 25 * MB);   // aliases h
  float* P = (float*)(ws + 89 * MB);
  u16* preA = (u16*)(ws + 89 * MB);     // aliases P

  weff_kernel<<<96, 256, 0, stream>>>(rmsw, Wdyn, WT);
  transpose_kernel<<<dim3(128, 32), 256, 0, stream>>>(W1, W1bt, 1024, 4096);
  transpose_kernel<<<dim3(32, 128), 256, 0, stream>>>(W2, W2bt, 4096, 1024);
  transpose_kernel<<<dim3(32, 128), 256, 0, stream>>>(Wout, Wobt, 4096, 1024);
  prep_tokens<<<8192, 256, 0, stream>>>(x, WT, bias_pre, bias_post, bias_res,
                                        a_pre, a_post, a_res, preA, scal);
  // GEMM1: h = gelu(preA @ W1 + b1)        M=8192 N=4096 K=1024 (no split)
  gemm_bf16<0><<<dim3(32, 64, 1), 256, 0, stream>>>(preA, W1bt, 1024, 1024, 4096, b1, h);
  // GEMM2 (split-K x2): P[z] = h @ W2 half-K partials   M=8192 N=1024 K=4096
  gemm_bf16<3><<<dim3(8, 64, 2), 256, 0, stream>>>(h, W2bt, 4096, 2048, 1024, nullptr, P);
  combine2_kernel<<<8192, 256, 0, stream>>>(P, x, b2, scal, merged);
  // GEMM3 (split-K x2): P[z] = merged @ Wout half-K partials   M=8192 N=1024 K=4096
  gemm_bf16<3><<<dim3(8, 64, 2), 256, 0, stream>>>(merged, Wobt, 4096, 2048, 1024, nullptr, P);
  combine3_kernel<<<8192, 256, 0, stream>>>(P, x, bout, out);
}